// Round 8
// baseline (6794.619 us; speedup 1.0000x reference)
//
#include <hip/hip_runtime.h>
#include <stdint.h>

#define M_NODES 100000
#define NUM_EDGES 3200000
#define IN_DIM 512
#define HIDDEN 256
#define NCLS 64
#define PANEL (M_NODES * 16)   // elements per 16-col bf16 panel

#define CH_BLOCKS 1024
#define CH_RANKS 256           // blocks per col-group
#define CH_TILES 6250          // 100000 / 16 rows per tile
#define CH_MAXT 25             // ceil(6250 / 256)

typedef __bf16 bf16x8 __attribute__((ext_vector_type(8)));
typedef float floatx4 __attribute__((ext_vector_type(4)));

// ---- workspace layout (bytes) ----
// rp   : int[100001]            @ 0         (pad bytes 400004..400016)
// bar  : int[2]                 @ 400008    (grid-barrier cnt/gen, in rp pad)
// w1t  : ushort[256*512]        @ 400016
// w2t  : ushort[64*256]         @ 662160
// h1   : ushort[100000*256]     @ 694928    (dead after gemm2; bB aliases it)
// bB   : ushort[4 panels]       @ 694928
// fA   : float[100000*64]       @ 51894928  (T0 fp32)
// fB   : float[100000*64]       @ 77494928  (unused)
// bA   : ushort[4 panels]       @ 103094928 (T0 bf16 panels from gemm2)
#define WS_ROWPTR 0
#define WS_BAR    400008
#define WS_W1T    400016
#define WS_W2T    662160
#define WS_H1     694928
#define WS_BB     694928
#define WS_FA     51894928
#define WS_FB     77494928
#define WS_BA     103094928

// ---------------- weight transpose + bf16 convert ----------------
__global__ __launch_bounds__(256) void prep_weights(
    const float* __restrict__ W1, const float* __restrict__ W2,
    unsigned short* __restrict__ w1t, unsigned short* __restrict__ w2t) {
  int tid = blockIdx.x * 256 + threadIdx.x;
  if (tid < IN_DIM * HIDDEN) {
    int n = tid >> 9;
    int k = tid & 511;
    __bf16 v = (__bf16)W1[k * HIDDEN + n];
    w1t[tid] = __builtin_bit_cast(unsigned short, v);
  } else {
    int idx = tid - IN_DIM * HIDDEN;
    if (idx < HIDDEN * NCLS) {
      int n = idx >> 8;
      int k = idx & 255;
      __bf16 v = (__bf16)W2[k * NCLS + n];
      w2t[idx] = __builtin_bit_cast(unsigned short, v);
    }
  }
}

// ---------------- row_ptr via binary search + barrier init ----------------
__global__ __launch_bounds__(256) void build_rowptr(
    const int* __restrict__ erow, int* __restrict__ rp, int* __restrict__ bar) {
  int r = blockIdx.x * 256 + threadIdx.x;
  if (r == 0) { bar[0] = 0; bar[1] = 0; }
  if (r > M_NODES) return;
  if (r == M_NODES) { rp[r] = NUM_EDGES; return; }
  int lo = 0, hi = NUM_EDGES;
  while (lo < hi) {
    int mid = (lo + hi) >> 1;
    if (erow[mid] < r) lo = mid + 1; else hi = mid;
  }
  rp[r] = lo;
}

// ---------------- GEMM1: h1 = relu(x @ W1 + b1), bf16 out ----------------
__global__ __launch_bounds__(256) void gemm1(
    const float* __restrict__ x, const unsigned short* __restrict__ w1t,
    const float* __restrict__ b1, unsigned short* __restrict__ h1) {
  __shared__ float xs[32 * 68];
  const int wave = threadIdx.x >> 6, lane = threadIdx.x & 63;
  const int m0 = blockIdx.x * 32;
  const int n0 = wave * 64;
  const int l15 = lane & 15, quad = lane >> 4;
  const int t = threadIdx.x;

  floatx4 pre[2];
#pragma unroll
  for (int j = 0; j < 2; j++) {
    const int i = t * 2 + j;
    pre[j] = *(const floatx4*)(x + (size_t)(m0 + (i >> 4)) * IN_DIM + (i & 15) * 4);
  }

  floatx4 acc[2][4] = {};
  for (int kb = 0; kb < IN_DIM; kb += 64) {
    __syncthreads();
#pragma unroll
    for (int j = 0; j < 2; j++) {
      const int i = t * 2 + j;
      *(floatx4*)(xs + (i >> 4) * 68 + (i & 15) * 4) = pre[j];
    }
    __syncthreads();
    if (kb + 64 < IN_DIM) {
#pragma unroll
      for (int j = 0; j < 2; j++) {
        const int i = t * 2 + j;
        pre[j] = *(const floatx4*)(x + (size_t)(m0 + (i >> 4)) * IN_DIM + kb + 64 + (i & 15) * 4);
      }
    }

    bf16x8 afrag[2][2];
    bf16x8 bfrag[2][4];
#pragma unroll
    for (int ks = 0; ks < 2; ks++) {
#pragma unroll
      for (int tm = 0; tm < 2; tm++) {
        const float* p = xs + (tm * 16 + l15) * 68 + ks * 32 + quad * 8;
        floatx4 a0 = *(const floatx4*)p;
        floatx4 a1 = *(const floatx4*)(p + 4);
        bf16x8 f;
        f[0] = (__bf16)a0[0]; f[1] = (__bf16)a0[1]; f[2] = (__bf16)a0[2]; f[3] = (__bf16)a0[3];
        f[4] = (__bf16)a1[0]; f[5] = (__bf16)a1[1]; f[6] = (__bf16)a1[2]; f[7] = (__bf16)a1[3];
        afrag[ks][tm] = f;
      }
      const int k = kb + ks * 32 + quad * 8;
#pragma unroll
      for (int tn = 0; tn < 4; tn++)
        bfrag[ks][tn] = *(const bf16x8*)(w1t + (size_t)(n0 + tn * 16 + l15) * IN_DIM + k);
    }
#pragma unroll
    for (int ks = 0; ks < 2; ks++)
#pragma unroll
      for (int tm = 0; tm < 2; tm++)
#pragma unroll
        for (int tn = 0; tn < 4; tn++)
          acc[tm][tn] = __builtin_amdgcn_mfma_f32_16x16x32_bf16(afrag[ks][tm], bfrag[ks][tn], acc[tm][tn], 0, 0, 0);
  }

#pragma unroll
  for (int tm = 0; tm < 2; tm++)
#pragma unroll
    for (int tn = 0; tn < 4; tn++) {
      const int col = n0 + tn * 16 + l15;
      const float bias = b1[col];
#pragma unroll
      for (int r = 0; r < 4; r++) {
        const int row = m0 + tm * 16 + quad * 4 + r;
        float v = acc[tm][tn][r] + bias;
        v = v > 0.0f ? v : 0.0f;
        __bf16 bv = (__bf16)v;
        h1[(size_t)row * HIDDEN + col] = __builtin_bit_cast(unsigned short, bv);
      }
    }
}

// ---------------- GEMM2: T0 = h1 @ W2 + b2 -> fp32 (row-major) + bf16 PANELS ----
__global__ __launch_bounds__(256) void gemm2(
    const unsigned short* __restrict__ h1, const unsigned short* __restrict__ w2t,
    const float* __restrict__ b2, float* __restrict__ t0f,
    unsigned short* __restrict__ t0b) {
  const int wave = threadIdx.x >> 6, lane = threadIdx.x & 63;
  const int m0 = blockIdx.x * 128 + wave * 32;
  if (m0 >= M_NODES) return;
  const int l15 = lane & 15, quad = lane >> 4;

  floatx4 acc[2][4] = {};
  for (int kb = 0; kb < HIDDEN; kb += 32) {
    const int k = kb + quad * 8;
    bf16x8 afrag[2], bfrag[4];
#pragma unroll
    for (int tm = 0; tm < 2; tm++)
      afrag[tm] = *(const bf16x8*)(h1 + (size_t)(m0 + tm * 16 + l15) * HIDDEN + k);
#pragma unroll
    for (int tn = 0; tn < 4; tn++)
      bfrag[tn] = *(const bf16x8*)(w2t + (size_t)(tn * 16 + l15) * HIDDEN + k);
#pragma unroll
    for (int tm = 0; tm < 2; tm++)
#pragma unroll
      for (int tn = 0; tn < 4; tn++)
        acc[tm][tn] = __builtin_amdgcn_mfma_f32_16x16x32_bf16(afrag[tm], bfrag[tn], acc[tm][tn], 0, 0, 0);
  }

#pragma unroll
  for (int tm = 0; tm < 2; tm++)
#pragma unroll
    for (int tn = 0; tn < 4; tn++) {
      const int col = tn * 16 + l15;
      const float bias = b2[col];
#pragma unroll
      for (int r = 0; r < 4; r++) {
        const int row = m0 + tm * 16 + quad * 4 + r;
        const float v = acc[tm][tn][r] + bias;
        t0f[(size_t)row * NCLS + col] = v;
        __bf16 bv = (__bf16)v;
        t0b[(size_t)tn * PANEL + (size_t)row * 16 + l15] = __builtin_bit_cast(unsigned short, bv);
      }
    }
}

// ---------------- device-scope grid barrier (all blocks co-resident) ----------
__device__ __forceinline__ void grid_barrier(int* cnt, int* gen) {
  __syncthreads();
  if (threadIdx.x == 0) {
    __threadfence();  // release: panel writes visible device-wide
    const int my = __hip_atomic_load(gen, __ATOMIC_RELAXED, __HIP_MEMORY_SCOPE_AGENT);
    const int prev = __hip_atomic_fetch_add(cnt, 1, __ATOMIC_ACQ_REL, __HIP_MEMORY_SCOPE_AGENT);
    if (prev == CH_BLOCKS - 1) {
      __hip_atomic_store(cnt, 0, __ATOMIC_RELAXED, __HIP_MEMORY_SCOPE_AGENT);
      __hip_atomic_fetch_add(gen, 1, __ATOMIC_RELEASE, __HIP_MEMORY_SCOPE_AGENT);
    } else {
      while (__hip_atomic_load(gen, __ATOMIC_RELAXED, __HIP_MEMORY_SCOPE_AGENT) == my)
        __builtin_amdgcn_s_sleep(2);
    }
    __threadfence();  // acquire: invalidate stale cached lines
  }
  __syncthreads();
}

// ---------------- panel gather: sum vals[e] * pan[cols[e]][c15] -------------
// edges via nontemporal loads (don't evict L2-resident panel)
__device__ __forceinline__ float gath(
    const int* __restrict__ rp, const int* __restrict__ cols,
    const float* __restrict__ vals, const unsigned short* __restrict__ pan,
    int r, int c15) {
  int e = rp[r];
  const int re = rp[r + 1];
  float a0 = 0, a1 = 0, a2 = 0, a3 = 0;
  for (; e + 4 <= re; e += 4) {
    const int c0 = __builtin_nontemporal_load(cols + e + 0);
    const int c1 = __builtin_nontemporal_load(cols + e + 1);
    const int c2 = __builtin_nontemporal_load(cols + e + 2);
    const int c3 = __builtin_nontemporal_load(cols + e + 3);
    const float v0 = __builtin_nontemporal_load(vals + e + 0);
    const float v1 = __builtin_nontemporal_load(vals + e + 1);
    const float v2 = __builtin_nontemporal_load(vals + e + 2);
    const float v3 = __builtin_nontemporal_load(vals + e + 3);
    const float g0 = (float)__builtin_bit_cast(__bf16, pan[(size_t)c0 * 16 + c15]);
    const float g1 = (float)__builtin_bit_cast(__bf16, pan[(size_t)c1 * 16 + c15]);
    const float g2 = (float)__builtin_bit_cast(__bf16, pan[(size_t)c2 * 16 + c15]);
    const float g3 = (float)__builtin_bit_cast(__bf16, pan[(size_t)c3 * 16 + c15]);
    a0 += v0 * g0; a1 += v1 * g1; a2 += v2 * g2; a3 += v3 * g3;
  }
  for (; e < re; ++e)
    a0 += vals[e] * (float)__builtin_bit_cast(__bf16, pan[(size_t)cols[e] * 16 + c15]);
  return (a0 + a1) + (a2 + a3);
}

// ---------------- fused persistent Chebyshev chain --------------------------
// 1024 blocks x 256 thr, 4 blocks/CU co-resident (LDS=0, VGPR<=128 forced).
// slot = b&7 -> XCD (launch-time round-robin, pinned since all co-resident);
// col group g = slot>>1: XCD pair {2g,2g+1} only gathers panel g (3.2 MB < L2).
// Lane owns (r, c) elements for all 8 steps: t_prev/t_cur/z in registers.
__global__ __launch_bounds__(256, 4) void cheb_chain(
    const int* __restrict__ rp, const int* __restrict__ cols,
    const float* __restrict__ vals, const float* __restrict__ t0f,
    const unsigned short* __restrict__ p0, unsigned short* __restrict__ pA,
    unsigned short* __restrict__ pB, const float* __restrict__ gamma,
    float* __restrict__ z, int* __restrict__ bar) {
  const int b = blockIdx.x;
  const int slot = b & 7;
  const int g = slot >> 1;
  const int rank = ((b >> 3) << 1) + (slot & 1);   // 0..255 within group
  const int l = threadIdx.x & 63;
  const int rsub = (threadIdx.x >> 6) * 4 + (l >> 4);  // 0..15
  const int c15 = l & 15;
  const int cg = g * 16 + c15;

  float tprev[CH_MAXT], tcur[CH_MAXT], zac[CH_MAXT];
  const float g0 = gamma[0], g1 = gamma[1];
  const unsigned short* pg0 = p0 + (size_t)g * PANEL;

  // ---- step 1: T1 = L T0 ; z = g0*T0 + g1*T1 ----
#pragma unroll
  for (int i = 0; i < CH_MAXT; i++) {
    const int tile = rank + i * CH_RANKS;
    if (tile < CH_TILES) {
      const int r = tile * 16 + rsub;
      const float tp = t0f[(size_t)r * NCLS + cg];
      const float s = gath(rp, cols, vals, pg0, r, c15);
      tprev[i] = tp;
      tcur[i] = s;
      zac[i] = g0 * tp + g1 * s;
      __bf16 bv = (__bf16)s;
      pA[(size_t)g * PANEL + (size_t)r * 16 + c15] = __builtin_bit_cast(unsigned short, bv);
    }
  }
  grid_barrier(bar, bar + 1);

  const unsigned short* src = pA;
  unsigned short* dst = pB;
#pragma unroll 1
  for (int k = 2; k <= 8; k++) {
    const float gk = gamma[k];
    const unsigned short* sg = src + (size_t)g * PANEL;
#pragma unroll
    for (int i = 0; i < CH_MAXT; i++) {
      const int tile = rank + i * CH_RANKS;
      if (tile < CH_TILES) {
        const int r = tile * 16 + rsub;
        const float s = gath(rp, cols, vals, sg, r, c15);
        const float tn = 2.0f * s - tprev[i];
        tprev[i] = tcur[i];
        tcur[i] = tn;
        zac[i] += gk * tn;
        if (k < 8) {
          __bf16 bv = (__bf16)tn;
          dst[(size_t)g * PANEL + (size_t)r * 16 + c15] = __builtin_bit_cast(unsigned short, bv);
        }
      }
    }
    if (k < 8) {
      grid_barrier(bar, bar + 1);
      const unsigned short* ts = src;
      src = dst;
      dst = (unsigned short*)ts;
    }
  }

#pragma unroll
  for (int i = 0; i < CH_MAXT; i++) {
    const int tile = rank + i * CH_RANKS;
    if (tile < CH_TILES) {
      const int r = tile * 16 + rsub;
      z[(size_t)r * NCLS + cg] = zac[i];
    }
  }
}

extern "C" void kernel_launch(void* const* d_in, const int* in_sizes, int n_in,
                              void* d_out, int out_size, void* d_ws, size_t ws_size,
                              hipStream_t stream) {
  const float* x     = (const float*)d_in[0];
  const int*   erow  = (const int*)d_in[1];
  const int*   ecol  = (const int*)d_in[2];
  const float* evals = (const float*)d_in[3];
  const float* W1    = (const float*)d_in[4];
  const float* b1    = (const float*)d_in[5];
  const float* W2    = (const float*)d_in[6];
  const float* b2    = (const float*)d_in[7];
  const float* gamma = (const float*)d_in[8];

  char* ws = (char*)d_ws;
  int*            rp  = (int*)(ws + WS_ROWPTR);
  int*            bar = (int*)(ws + WS_BAR);
  unsigned short* w1t = (unsigned short*)(ws + WS_W1T);
  unsigned short* w2t = (unsigned short*)(ws + WS_W2T);
  unsigned short* h1  = (unsigned short*)(ws + WS_H1);
  float*          fA  = (float*)(ws + WS_FA);
  unsigned short* bA  = (unsigned short*)(ws + WS_BA);
  unsigned short* bB  = (unsigned short*)(ws + WS_BB);
  float*          z   = (float*)d_out;

  prep_weights<<<576, 256, 0, stream>>>(W1, W2, w1t, w2t);
  build_rowptr<<<(M_NODES + 256) / 256, 256, 0, stream>>>(erow, rp, bar);
  gemm1<<<M_NODES / 32, 256, 0, stream>>>(x, w1t, b1, h1);
  gemm2<<<(M_NODES + 127) / 128, 256, 0, stream>>>(h1, w2t, b2, fA, bA);

  // fused chain: step1 gathers bA panels -> writes bB; then ping-pong bB/bA.
  cheb_chain<<<CH_BLOCKS, 256, 0, stream>>>(rp, ecol, evals, fA, bA, bB, bA,
                                            gamma, z, bar);
}